// Round 2
// baseline (906.122 us; speedup 1.0000x reference)
//
#include <hip/hip_runtime.h>
#include <math.h>

#define BB 64
#define NN 1024
#define EPSV 1e-5f

// ---------------------------------------------------------------------------
// Kernel 1: per-batch normalize e -> x0 (two-pass mean/std, matches jnp.std)
// ---------------------------------------------------------------------------
__global__ __launch_bounds__(256) void norm_kernel(const float* __restrict__ e,
                                                   float* __restrict__ x0) {
  int b = blockIdx.x;
  int tid = threadIdx.x;
  __shared__ float row[NN];
  __shared__ float red[256];
  const float* er = e + (size_t)b * NN;

  float s = 0.f;
  for (int i = tid; i < NN; i += 256) { float v = er[i]; row[i] = v; s += v; }
  red[tid] = s; __syncthreads();
  for (int off = 128; off > 0; off >>= 1) {
    if (tid < off) red[tid] += red[tid + off];
    __syncthreads();
  }
  float mu = red[0] * (1.f / NN);
  __syncthreads();

  float s2 = 0.f;
  for (int i = tid; i < NN; i += 256) { float d = row[i] - mu; s2 += d * d; }
  red[tid] = s2; __syncthreads();
  for (int off = 128; off > 0; off >>= 1) {
    if (tid < off) red[tid] += red[tid + off];
    __syncthreads();
  }
  float sd = sqrtf(red[0] * (1.f / NN));
  float inv = 1.f / (sd + EPSV);
  for (int i = tid; i < NN; i += 256) x0[(size_t)b * NN + i] = (row[i] - mu) * inv;
}

// ---------------------------------------------------------------------------
// Kernel 2: t = x @ adj with adj recomputed on the fly.
// Layouts are transposed: xt, tt are (B, N, C) so per-n channel reads are
// wave-uniform -> scalar loads; inner loop is v_fmac(v, s, v) with no LDS.
// One thread per output column m; CG channels per block (blockIdx.z).
// ---------------------------------------------------------------------------
template<int C, int CG>
__global__ __launch_bounds__(256) void gather_kernel(
    const float* __restrict__ xt,   // (B, N, C)
    const float* __restrict__ phi,  // (B, N)
    const float* __restrict__ eta,  // (B, N)
    float* __restrict__ tt)         // (B, N, C)
{
  int b = blockIdx.y;
  int m = blockIdx.x * 256 + threadIdx.x;
  int c0 = blockIdx.z * CG;

  const float* phb = phi + (size_t)b * NN;
  const float* etb = eta + (size_t)b * NN;
  float phm = phb[m];
  float etm = etb[m];

  float acc[CG];
#pragma unroll
  for (int c = 0; c < CG; ++c) acc[c] = 0.f;

  const float* xb = xt + (size_t)b * NN * C + c0;

  for (int n = 0; n < NN; ++n) {
    float dp = phb[n] - phm;           // uniform scalar load
    float de = etb[n] - etm;           // uniform scalar load
    float a = __expf(-(dp * dp + de * de));
    const float* xr = xb + (size_t)n * C;  // uniform base -> s_load
#pragma unroll
    for (int c = 0; c < CG; ++c) acc[c] = fmaf(xr[c], a, acc[c]);
  }

  float* tr = tt + ((size_t)b * NN + m) * C + c0;
#pragma unroll
  for (int c = 0; c < CG; ++c) tr[c] = acc[c];
}

// ---------------------------------------------------------------------------
// Kernel 3: z = act(W @ concat(x, t) + bias)
// W is (O, 2C): first C columns hit x, next C hit t. W/bias reads uniform ->
// scalar loads; x/t columns held in registers.
// ---------------------------------------------------------------------------
template<int C, int O, bool RELU>
__global__ __launch_bounds__(256) void proj_kernel(
    const float* __restrict__ xt,   // (B, N, C)
    const float* __restrict__ tt,   // (B, N, C)
    const float* __restrict__ Wm,   // (O, 2C)
    const float* __restrict__ bias, // (O)
    float* __restrict__ zt)         // (B, N, O)
{
  int b = blockIdx.y;
  int m = blockIdx.x * 256 + threadIdx.x;

  const float* xr = xt + ((size_t)b * NN + m) * C;
  const float* tr = tt + ((size_t)b * NN + m) * C;
  float xv[C], tv[C];
#pragma unroll
  for (int c = 0; c < C; ++c) { xv[c] = xr[c]; tv[c] = tr[c]; }

  float* zr = zt + ((size_t)b * NN + m) * O;
  for (int o = 0; o < O; ++o) {
    const float* wr = Wm + (size_t)o * 2 * C;   // uniform -> s_load
    float z = bias[o];
#pragma unroll
    for (int c = 0; c < C; ++c) z = fmaf(wr[c], xv[c], z);
#pragma unroll
    for (int c = 0; c < C; ++c) z = fmaf(wr[C + c], tv[c], z);
    zr[o] = RELU ? fmaxf(z, 0.f) : z;
  }
}

// ---------------------------------------------------------------------------
// Kernel 4: out[b] = sigmoid(mean_n z[b][n][0])   (O==1, stride 1)
// ---------------------------------------------------------------------------
__global__ __launch_bounds__(256) void out_kernel(const float* __restrict__ z,
                                                  float* __restrict__ out) {
  int b = blockIdx.x;
  int tid = threadIdx.x;
  __shared__ float red[256];
  float s = 0.f;
  for (int i = tid; i < NN; i += 256) s += z[(size_t)b * NN + i];
  red[tid] = s; __syncthreads();
  for (int off = 128; off > 0; off >>= 1) {
    if (tid < off) red[tid] += red[tid + off];
    __syncthreads();
  }
  if (tid == 0) {
    float mval = red[0] * (1.f / NN);
    out[b] = 1.f / (1.f + __expf(-mval));
  }
}

// ---------------------------------------------------------------------------
extern "C" void kernel_launch(void* const* d_in, const int* in_sizes, int n_in,
                              void* d_out, int out_size, void* d_ws, size_t ws_size,
                              hipStream_t stream) {
  const float* e   = (const float*)d_in[0];
  const float* phi = (const float*)d_in[1];
  const float* eta = (const float*)d_in[2];
  const float* W0  = (const float*)d_in[3];
  const float* b0  = (const float*)d_in[4];
  const float* W1  = (const float*)d_in[5];
  const float* b1  = (const float*)d_in[6];
  const float* W2  = (const float*)d_in[7];
  const float* b2  = (const float*)d_in[8];
  const float* W3  = (const float*)d_in[9];
  const float* b3  = (const float*)d_in[10];

  float* ws = (float*)d_ws;
  const size_t CAP = (size_t)BB * NN * 64;  // 4M floats per buffer
  float* X0 = ws;            // norm out (C=1), L1 out (64), L3 out (1)
  float* X1 = ws + CAP;      // L0 out (32), L2 out (64)
  float* TT = ws + 2 * CAP;  // gather scratch (up to 64 ch)

  dim3 blk(256);
  dim3 g1(NN / 256, BB, 1);   // z = 1 channel group
  dim3 g2(NN / 256, BB, 2);   // z = 2 channel groups (C=64)

  norm_kernel<<<BB, blk, 0, stream>>>(e, X0);

  // Layer 0: C=1 -> O=32, relu
  gather_kernel<1, 1><<<g1, blk, 0, stream>>>(X0, phi, eta, TT);
  proj_kernel<1, 32, true><<<g1, blk, 0, stream>>>(X0, TT, W0, b0, X1);

  // Layer 1: C=32 -> O=64, relu
  gather_kernel<32, 32><<<g1, blk, 0, stream>>>(X1, phi, eta, TT);
  proj_kernel<32, 64, true><<<g1, blk, 0, stream>>>(X1, TT, W1, b1, X0);

  // Layer 2: C=64 -> O=64, relu
  gather_kernel<64, 32><<<g2, blk, 0, stream>>>(X0, phi, eta, TT);
  proj_kernel<64, 64, true><<<g1, blk, 0, stream>>>(X0, TT, W2, b2, X1);

  // Layer 3: C=64 -> O=1, no relu
  gather_kernel<64, 32><<<g2, blk, 0, stream>>>(X1, phi, eta, TT);
  proj_kernel<64, 1, false><<<g1, blk, 0, stream>>>(X1, TT, W3, b3, X0);

  out_kernel<<<BB, blk, 0, stream>>>(X0, (float*)d_out);
}

// Round 3
// 702.381 us; speedup vs baseline: 1.2901x; 1.2901x over previous
//
#include <hip/hip_runtime.h>
#include <math.h>

#define BB 64
#define NN 1024
#define EPSV 1e-5f

// ---------------------------------------------------------------------------
// Kernel 1: per-batch normalize e -> x0 (two-pass mean/std, matches jnp.std)
// ---------------------------------------------------------------------------
__global__ __launch_bounds__(256) void norm_kernel(const float* __restrict__ e,
                                                   float* __restrict__ x0) {
  int b = blockIdx.x;
  int tid = threadIdx.x;
  __shared__ float row[NN];
  __shared__ float red[256];
  const float* er = e + (size_t)b * NN;

  float s = 0.f;
  for (int i = tid; i < NN; i += 256) { float v = er[i]; row[i] = v; s += v; }
  red[tid] = s; __syncthreads();
  for (int off = 128; off > 0; off >>= 1) {
    if (tid < off) red[tid] += red[tid + off];
    __syncthreads();
  }
  float mu = red[0] * (1.f / NN);
  __syncthreads();

  float s2 = 0.f;
  for (int i = tid; i < NN; i += 256) { float d = row[i] - mu; s2 += d * d; }
  red[tid] = s2; __syncthreads();
  for (int off = 128; off > 0; off >>= 1) {
    if (tid < off) red[tid] += red[tid + off];
    __syncthreads();
  }
  float sd = sqrtf(red[0] * (1.f / NN));
  float inv = 1.f / (sd + EPSV);
  for (int i = tid; i < NN; i += 256) x0[(size_t)b * NN + i] = (row[i] - mu) * inv;
}

// ---------------------------------------------------------------------------
// Kernel 2 (v2): t = x @ adj, adj recomputed on the fly, LDS-staged.
//   - x tile (NT rows x C ch) + phi/eta staged in LDS via coalesced float4.
//   - thread owns MT m-columns x CPT channels -> MT*CPT fp32 accumulators.
//   - each wave = one channel group -> LDS x reads are wave-broadcast.
// Layouts: xt, tt are (B, N, C).
// ---------------------------------------------------------------------------
template<int C, int CPT, int MT>
__global__ __launch_bounds__(256) void gather_kernel(
    const float* __restrict__ xt,   // (B, N, C)
    const float* __restrict__ phi,  // (B, N)
    const float* __restrict__ eta,  // (B, N)
    float* __restrict__ tt)         // (B, N, C)
{
  constexpr int CG = C / CPT;        // channel groups
  constexpr int MTH = 256 / CG;      // m-threads per group
  constexpr int MTILE = MTH * MT;    // m-columns per block
  constexpr int NT = 128;            // n-tile

  __shared__ float sx[NT * C];
  __shared__ float2 spe[NT];

  int b = blockIdx.y;
  int m0 = blockIdx.x * MTILE;
  int tid = threadIdx.x;
  int mi = tid % MTH;                // within-group m index
  int cg = tid / MTH;                // wave-uniform channel group
  int c0 = cg * CPT;

  const float* phb = phi + (size_t)b * NN;
  const float* etb = eta + (size_t)b * NN;

  float phm[MT], etm[MT];
#pragma unroll
  for (int j = 0; j < MT; ++j) {
    int m = m0 + mi + j * MTH;
    phm[j] = phb[m];
    etm[j] = etb[m];
  }

  float acc[MT][CPT];
#pragma unroll
  for (int j = 0; j < MT; ++j)
#pragma unroll
    for (int c = 0; c < CPT; ++c) acc[j][c] = 0.f;

  const float* xb = xt + (size_t)b * NN * C;

  for (int n0 = 0; n0 < NN; n0 += NT) {
    __syncthreads();   // previous tile fully consumed
    // stage x tile (coalesced float4)
    const float4* src = (const float4*)(xb + (size_t)n0 * C);
    for (int i = tid; i < NT * C / 4; i += 256) ((float4*)sx)[i] = src[i];
    // stage phi/eta interleaved
    for (int i = tid; i < NT; i += 256)
      spe[i] = make_float2(phb[n0 + i], etb[n0 + i]);
    __syncthreads();

#pragma unroll 4
    for (int n = 0; n < NT; ++n) {
      float2 pe = spe[n];
      float a[MT];
#pragma unroll
      for (int j = 0; j < MT; ++j) {
        float dp = pe.x - phm[j];
        float de = pe.y - etm[j];
        a[j] = __expf(-(dp * dp + de * de));
      }
      if constexpr (CPT % 4 == 0) {
        const float4* xr4 = (const float4*)(sx + n * C + c0);  // wave-broadcast
#pragma unroll
        for (int k = 0; k < CPT / 4; ++k) {
          float4 xv = xr4[k];
#pragma unroll
          for (int j = 0; j < MT; ++j) {
            acc[j][4 * k + 0] = fmaf(a[j], xv.x, acc[j][4 * k + 0]);
            acc[j][4 * k + 1] = fmaf(a[j], xv.y, acc[j][4 * k + 1]);
            acc[j][4 * k + 2] = fmaf(a[j], xv.z, acc[j][4 * k + 2]);
            acc[j][4 * k + 3] = fmaf(a[j], xv.w, acc[j][4 * k + 3]);
          }
        }
      } else {
#pragma unroll
        for (int c = 0; c < CPT; ++c) {
          float xv = sx[n * C + c0 + c];
#pragma unroll
          for (int j = 0; j < MT; ++j) acc[j][c] = fmaf(a[j], xv, acc[j][c]);
        }
      }
    }
  }

#pragma unroll
  for (int j = 0; j < MT; ++j) {
    int m = m0 + mi + j * MTH;
    float* tr = tt + ((size_t)b * NN + m) * C + c0;
#pragma unroll
    for (int c = 0; c < CPT; ++c) tr[c] = acc[j][c];
  }
}

// ---------------------------------------------------------------------------
// Kernel 3: z = act(W @ concat(x, t) + bias)
// ---------------------------------------------------------------------------
template<int C, int O, bool RELU>
__global__ __launch_bounds__(256) void proj_kernel(
    const float* __restrict__ xt,   // (B, N, C)
    const float* __restrict__ tt,   // (B, N, C)
    const float* __restrict__ Wm,   // (O, 2C)
    const float* __restrict__ bias, // (O)
    float* __restrict__ zt)         // (B, N, O)
{
  int b = blockIdx.y;
  int m = blockIdx.x * 256 + threadIdx.x;

  const float* xr = xt + ((size_t)b * NN + m) * C;
  const float* tr = tt + ((size_t)b * NN + m) * C;
  float xv[C], tv[C];
#pragma unroll
  for (int c = 0; c < C; ++c) { xv[c] = xr[c]; tv[c] = tr[c]; }

  float* zr = zt + ((size_t)b * NN + m) * O;
  for (int o = 0; o < O; ++o) {
    const float* wr = Wm + (size_t)o * 2 * C;   // uniform -> s_load
    float z = bias[o];
#pragma unroll
    for (int c = 0; c < C; ++c) z = fmaf(wr[c], xv[c], z);
#pragma unroll
    for (int c = 0; c < C; ++c) z = fmaf(wr[C + c], tv[c], z);
    zr[o] = RELU ? fmaxf(z, 0.f) : z;
  }
}

// ---------------------------------------------------------------------------
// Kernel 4: out[b] = sigmoid(mean_n z[b][n][0])
// ---------------------------------------------------------------------------
__global__ __launch_bounds__(256) void out_kernel(const float* __restrict__ z,
                                                  float* __restrict__ out) {
  int b = blockIdx.x;
  int tid = threadIdx.x;
  __shared__ float red[256];
  float s = 0.f;
  for (int i = tid; i < NN; i += 256) s += z[(size_t)b * NN + i];
  red[tid] = s; __syncthreads();
  for (int off = 128; off > 0; off >>= 1) {
    if (tid < off) red[tid] += red[tid + off];
    __syncthreads();
  }
  if (tid == 0) {
    float mval = red[0] * (1.f / NN);
    out[b] = 1.f / (1.f + __expf(-mval));
  }
}

// ---------------------------------------------------------------------------
extern "C" void kernel_launch(void* const* d_in, const int* in_sizes, int n_in,
                              void* d_out, int out_size, void* d_ws, size_t ws_size,
                              hipStream_t stream) {
  const float* e   = (const float*)d_in[0];
  const float* phi = (const float*)d_in[1];
  const float* eta = (const float*)d_in[2];
  const float* W0  = (const float*)d_in[3];
  const float* b0  = (const float*)d_in[4];
  const float* W1  = (const float*)d_in[5];
  const float* b1  = (const float*)d_in[6];
  const float* W2  = (const float*)d_in[7];
  const float* b2  = (const float*)d_in[8];
  const float* W3  = (const float*)d_in[9];
  const float* b3  = (const float*)d_in[10];

  float* ws = (float*)d_ws;
  const size_t CAP = (size_t)BB * NN * 64;  // 4M floats per buffer
  float* X0 = ws;            // norm out (C=1), L1 out (64), L3 out (1)
  float* X1 = ws + CAP;      // L0 out (32), L2 out (64)
  float* TT = ws + 2 * CAP;  // gather scratch (up to 64 ch)

  dim3 blk(256);
  dim3 gp(NN / 256, BB);      // proj grids: 1 thread per node

  norm_kernel<<<BB, blk, 0, stream>>>(e, X0);

  // Layer 0: C=1 -> O=32, relu.  gather<1,1,1>: MTILE=256, grid (4,64)
  gather_kernel<1, 1, 1><<<dim3(NN / 256, BB), blk, 0, stream>>>(X0, phi, eta, TT);
  proj_kernel<1, 32, true><<<gp, blk, 0, stream>>>(X0, TT, W0, b0, X1);

  // Layer 1: C=32 -> O=64, relu.  gather<32,16,1>: MTILE=128, grid (8,64)
  gather_kernel<32, 16, 1><<<dim3(NN / 128, BB), blk, 0, stream>>>(X1, phi, eta, TT);
  proj_kernel<32, 64, true><<<gp, blk, 0, stream>>>(X1, TT, W1, b1, X0);

  // Layer 2: C=64 -> O=64, relu.  gather<64,16,2>: MTILE=128, grid (8,64)
  gather_kernel<64, 16, 2><<<dim3(NN / 128, BB), blk, 0, stream>>>(X0, phi, eta, TT);
  proj_kernel<64, 64, true><<<gp, blk, 0, stream>>>(X0, TT, W2, b2, X1);

  // Layer 3: C=64 -> O=1, no relu
  gather_kernel<64, 16, 2><<<dim3(NN / 128, BB), blk, 0, stream>>>(X1, phi, eta, TT);
  proj_kernel<64, 1, false><<<gp, blk, 0, stream>>>(X1, TT, W3, b3, X0);

  out_kernel<<<BB, blk, 0, stream>>>(X0, (float*)d_out);
}

// Round 4
// 220.092 us; speedup vs baseline: 4.1170x; 3.1913x over previous
//
#include <hip/hip_runtime.h>
#include <hip/hip_bf16.h>
#include <math.h>

#define BB 64
#define NN 1024
#define EPSV 1e-5f

typedef unsigned short u16;
typedef __attribute__((ext_vector_type(8))) short short8;
typedef __attribute__((ext_vector_type(4))) float f32x4;

#define GLOBAL_AS __attribute__((address_space(1)))
#define LDS_AS __attribute__((address_space(3)))

static __device__ __forceinline__ void gload_lds16(const void* g, void* l) {
  __builtin_amdgcn_global_load_lds((const GLOBAL_AS unsigned int*)g,
                                   (LDS_AS unsigned int*)l, 16, 0, 0);
}

static __device__ __forceinline__ u16 f2bf(float f) {
  __hip_bfloat16 h = __float2bfloat16(f);   // RNE
  union { __hip_bfloat16 h; u16 s; } u; u.h = h; return u.s;
}
static __device__ __forceinline__ float bf2f(u16 s) {
  unsigned int u = ((unsigned int)s) << 16;
  union { unsigned int u; float f; } c; c.u = u; return c.f;
}

// ---------------------------------------------------------------------------
// Kernel 1: per-batch normalize e -> x0 fp32 (B,N) + x0bf (B,16,N) bf16
// (channels 1..15 zero-padded so the MFMA gather can run CB=16)
// ---------------------------------------------------------------------------
__global__ __launch_bounds__(256) void norm_kernel(const float* __restrict__ e,
                                                   float* __restrict__ x0,
                                                   u16* __restrict__ x0bf) {
  int b = blockIdx.x;
  int tid = threadIdx.x;
  __shared__ float row[NN];
  __shared__ float red[256];
  const float* er = e + (size_t)b * NN;

  float s = 0.f;
  for (int i = tid; i < NN; i += 256) { float v = er[i]; row[i] = v; s += v; }
  red[tid] = s; __syncthreads();
  for (int off = 128; off > 0; off >>= 1) {
    if (tid < off) red[tid] += red[tid + off];
    __syncthreads();
  }
  float mu = red[0] * (1.f / NN);
  __syncthreads();

  float s2 = 0.f;
  for (int i = tid; i < NN; i += 256) { float d = row[i] - mu; s2 += d * d; }
  red[tid] = s2; __syncthreads();
  for (int off = 128; off > 0; off >>= 1) {
    if (tid < off) red[tid] += red[tid + off];
    __syncthreads();
  }
  float sd = sqrtf(red[0] * (1.f / NN));
  float inv = 1.f / (sd + EPSV);
  for (int i = tid; i < NN; i += 256) {
    float v = (row[i] - mu) * inv;
    x0[(size_t)b * NN + i] = v;
    x0bf[(size_t)b * 16 * NN + i] = f2bf(v);
  }
  for (int c = 1; c < 16; ++c)
    for (int i = tid; i < NN; i += 256)
      x0bf[((size_t)b * 16 + c) * NN + i] = 0;
}

// ---------------------------------------------------------------------------
// Kernel 2 (v3): MFMA gather.  t^T = adj @ x^T per batch (adj symmetric).
//   A (adj 16m x 32k) generated IN REGISTERS in fragment layout:
//     lane l computes A[l&15][8*(l>>4)+j] = exp(-d2(m,n)), j=0..7
//   B (x^T 32k x 16c): xbf is channel-major (B,CB,N) so lane's 8 k-elems are
//     16 contiguous bytes in the LDS slab -> one ds_read_b128 per c-tile.
//   Slab (32n x CB) staged via global_load_lds(16B), double-buffered.
// Output tt: (B,N,CB) bf16.
// ---------------------------------------------------------------------------
template<int CB>
__global__ __launch_bounds__(256) void gatherT_kernel(
    const u16* __restrict__ xbf,    // (B, CB, N) bf16 bits
    const float* __restrict__ phi,  // (B, N)
    const float* __restrict__ eta,  // (B, N)
    u16* __restrict__ tt)           // (B, N, CB) bf16 bits
{
  constexpr int NCT = CB / 16;      // c-tiles per wave
  constexpr int SLAB = 32 * CB;     // bf16 elems per slab
  constexpr int STH = CB * 4;       // staging threads (16B each)

  __shared__ float2 pe[NN];         // 8KB: (phi, eta) per node
  __shared__ u16 slab[2][SLAB];     // CB=64: 2x4KB

  int b = blockIdx.y;
  int m0 = blockIdx.x * 64;
  int tid = threadIdx.x;
  int lane = tid & 63;
  int w = tid >> 6;
  int g = lane >> 4;                // quarter-wave = k-octet / D-row-quad
  int cl = lane & 15;

  const float* phb = phi + (size_t)b * NN;
  const float* etb = eta + (size_t)b * NN;

  for (int i = tid; i < NN; i += 256)
    pe[i] = make_float2(phb[i], etb[i]);

  int m_lane = m0 + w * 16 + cl;    // A-row owned by this lane
  float phm = phb[m_lane];
  float etm = etb[m_lane];

  f32x4 acc[NCT];
#pragma unroll
  for (int ci = 0; ci < NCT; ++ci) acc[ci] = (f32x4){0.f, 0.f, 0.f, 0.f};

  const u16* xb = xbf + (size_t)b * CB * NN;

  // stage slab for k-step 0
  if (tid < STH) {
    int gg = tid / CB, cc = tid % CB;
    gload_lds16(xb + (size_t)cc * NN + gg * 8, &slab[0][tid * 8]);
  }
  __syncthreads();

  for (int s = 0; s < NN / 32; ++s) {
    int cur = s & 1;
    if (s + 1 < NN / 32) {
      if (tid < STH) {
        int gg = tid / CB, cc = tid % CB;
        gload_lds16(xb + (size_t)cc * NN + (s + 1) * 32 + gg * 8,
                    &slab[cur ^ 1][tid * 8]);
      }
    }
    int n0 = s * 32;

    // --- A fragment: 8 adj entries per lane, rows=cl, k=8g+j ---
    const float2* pp = &pe[n0 + 8 * g];
    union { short8 v; u16 h[8]; } af;
#pragma unroll
    for (int j = 0; j < 8; ++j) {
      float2 q = pp[j];
      float dp = q.x - phm;
      float de = q.y - etm;
      float d2 = fmaf(dp, dp, de * de);
      af.h[j] = f2bf(__expf(-d2));
    }

    // --- B fragments + MFMA ---
#pragma unroll
    for (int ci = 0; ci < NCT; ++ci) {
      const short8* bp = (const short8*)&slab[cur][(g * CB + ci * 16 + cl) * 8];
      acc[ci] = __builtin_amdgcn_mfma_f32_16x16x32_bf16(af.v, *bp, acc[ci], 0, 0, 0);
    }
    __syncthreads();
  }

  // epilogue: D row=(lane>>4)*4+reg, col=lane&15
#pragma unroll
  for (int ci = 0; ci < NCT; ++ci)
#pragma unroll
    for (int r = 0; r < 4; ++r) {
      int m = m0 + w * 16 + g * 4 + r;
      tt[((size_t)b * NN + m) * CB + ci * 16 + cl] = f2bf(acc[ci][r]);
    }
}

// ---------------------------------------------------------------------------
// Kernel 3 (v3): z = act(W @ concat(x, t) + bias), W staged in LDS,
// O split across blockIdx.z for occupancy.  Also emits z^T bf16 (B,O,N)
// for the next gather's channel-major operand.
// ---------------------------------------------------------------------------
template<int C, int O, int TS, int OS, bool RELU>
__global__ __launch_bounds__(256) void proj_kernel(
    const float* __restrict__ xt,   // (B, N, C) fp32
    const u16* __restrict__ tt,     // (B, N, TS) bf16, first C cols valid
    const float* __restrict__ Wm,   // (O, 2C)
    const float* __restrict__ bias, // (O)
    float* __restrict__ zt,         // (B, N, O) fp32
    u16* __restrict__ zbf)          // (B, O, N) bf16
{
  constexpr int OC = O / OS;
  int b = blockIdx.y;
  int oc0 = blockIdx.z * OC;
  int m = blockIdx.x * 256 + threadIdx.x;

  __shared__ float sW[OC * 2 * C];
  __shared__ float sB[OC];
  for (int i = threadIdx.x; i < OC * 2 * C; i += 256)
    sW[i] = Wm[(size_t)oc0 * 2 * C + i];
  for (int i = threadIdx.x; i < OC; i += 256) sB[i] = bias[oc0 + i];
  __syncthreads();

  const float* xr = xt + ((size_t)b * NN + m) * C;
  const u16* tr = tt + ((size_t)b * NN + m) * TS;
  float xv[C], tv[C];
#pragma unroll
  for (int c = 0; c < C; ++c) { xv[c] = xr[c]; tv[c] = bf2f(tr[c]); }

  float* zr = zt + ((size_t)b * NN + m) * O;
  for (int o = 0; o < OC; ++o) {
    const float* wr = &sW[o * 2 * C];    // LDS broadcast
    float z = sB[o];
#pragma unroll
    for (int c = 0; c < C; ++c) z = fmaf(wr[c], xv[c], z);
#pragma unroll
    for (int c = 0; c < C; ++c) z = fmaf(wr[C + c], tv[c], z);
    if (RELU) z = fmaxf(z, 0.f);
    zr[oc0 + o] = z;
    zbf[((size_t)b * O + oc0 + o) * NN + m] = f2bf(z);
  }
}

// ---------------------------------------------------------------------------
// Kernel 4: fused layer-3 projection (C=64 -> O=1) + mean + sigmoid
// ---------------------------------------------------------------------------
__global__ __launch_bounds__(256) void proj3out_kernel(
    const float* __restrict__ xt,   // (B, N, 64)
    const u16* __restrict__ tt,     // (B, N, 64) bf16
    const float* __restrict__ Wm,   // (1, 128)
    const float* __restrict__ bias, // (1)
    float* __restrict__ out)        // (B)
{
  int b = blockIdx.x;
  int tid = threadIdx.x;
  __shared__ float sW[128];
  __shared__ float red[256];
  if (tid < 128) sW[tid] = Wm[tid];
  __syncthreads();

  float s = 0.f;
  for (int k = 0; k < 4; ++k) {
    int m = k * 256 + tid;
    const float* xr = xt + ((size_t)b * NN + m) * 64;
    const u16* tr = tt + ((size_t)b * NN + m) * 64;
    float z = bias[0];
#pragma unroll
    for (int c = 0; c < 64; ++c) z = fmaf(sW[c], xr[c], z);
#pragma unroll
    for (int c = 0; c < 64; ++c) z = fmaf(sW[64 + c], bf2f(tr[c]), z);
    s += z;
  }
  red[tid] = s; __syncthreads();
  for (int off = 128; off > 0; off >>= 1) {
    if (tid < off) red[tid] += red[tid + off];
    __syncthreads();
  }
  if (tid == 0) {
    float mval = red[0] * (1.f / NN);
    out[b] = 1.f / (1.f + __expf(-mval));
  }
}

// ---------------------------------------------------------------------------
extern "C" void kernel_launch(void* const* d_in, const int* in_sizes, int n_in,
                              void* d_out, int out_size, void* d_ws, size_t ws_size,
                              hipStream_t stream) {
  const float* e   = (const float*)d_in[0];
  const float* phi = (const float*)d_in[1];
  const float* eta = (const float*)d_in[2];
  const float* W0  = (const float*)d_in[3];
  const float* b0  = (const float*)d_in[4];
  const float* W1  = (const float*)d_in[5];
  const float* b1  = (const float*)d_in[6];
  const float* W2  = (const float*)d_in[7];
  const float* b2  = (const float*)d_in[8];
  const float* W3  = (const float*)d_in[9];
  const float* b3  = (const float*)d_in[10];

  // ws layout (48 MB total, same footprint as previous passing rounds):
  //  [0,8M)   TT   (B,N,64) bf16   gather output (per-layer scratch)
  //  [8,24M)  ZA   fp32: X0 (B,N) then X2 (B,N,64)
  //  [24,40M) ZB   fp32: X1 (B,N,32) then X3 (B,N,64)
  //  [40,48M) XBF  bf16 channel-major: x0bf(B,16,N)/X1bf(B,32,N)/X2bf/X3bf(B,64,N)
  char* wsb = (char*)d_ws;
  u16*   TT  = (u16*)(wsb);
  float* ZA  = (float*)(wsb + (size_t)(8u << 20));
  float* ZB  = (float*)(wsb + (size_t)(24u << 20));
  u16*   XBF = (u16*)(wsb + (size_t)(40u << 20));

  dim3 blk(256);
  dim3 gg(NN / 64, BB);   // gather grid: 1024 blocks

  norm_kernel<<<BB, blk, 0, stream>>>(e, ZA, XBF);

  // Layer 0: C=1 (padded to 16) -> O=32, relu
  gatherT_kernel<16><<<gg, blk, 0, stream>>>(XBF, phi, eta, TT);
  proj_kernel<1, 32, 16, 1, true><<<dim3(4, BB, 1), blk, 0, stream>>>(ZA, TT, W0, b0, ZB, XBF);

  // Layer 1: C=32 -> O=64, relu
  gatherT_kernel<32><<<gg, blk, 0, stream>>>(XBF, phi, eta, TT);
  proj_kernel<32, 64, 32, 2, true><<<dim3(4, BB, 2), blk, 0, stream>>>(ZB, TT, W1, b1, ZA, XBF);

  // Layer 2: C=64 -> O=64, relu
  gatherT_kernel<64><<<gg, blk, 0, stream>>>(XBF, phi, eta, TT);
  proj_kernel<64, 64, 64, 2, true><<<dim3(4, BB, 2), blk, 0, stream>>>(ZA, TT, W2, b2, ZB, XBF);

  // Layer 3: C=64 -> O=1 (+ mean + sigmoid, fused)
  gatherT_kernel<64><<<gg, blk, 0, stream>>>(XBF, phi, eta, TT);
  proj3out_kernel<<<BB, blk, 0, stream>>>(ZB, TT, W3, b3, (float*)d_out);
}

// Round 5
// 144.279 us; speedup vs baseline: 6.2804x; 1.5255x over previous
//
#include <hip/hip_runtime.h>
#include <hip/hip_bf16.h>
#include <math.h>

#define BB 64
#define NN 1024
#define EPSV 1e-5f

typedef unsigned short u16;
typedef __attribute__((ext_vector_type(8))) short short8;
typedef __attribute__((ext_vector_type(4))) float f32x4;

#define GLOBAL_AS __attribute__((address_space(1)))
#define LDS_AS __attribute__((address_space(3)))

static __device__ __forceinline__ void gload_lds16(const void* g, void* l) {
  __builtin_amdgcn_global_load_lds((const GLOBAL_AS unsigned int*)g,
                                   (LDS_AS unsigned int*)l, 16, 0, 0);
}

static __device__ __forceinline__ u16 f2bf(float f) {
  __hip_bfloat16 h = __float2bfloat16(f);   // RNE
  union { __hip_bfloat16 h; u16 s; } u; u.h = h; return u.s;
}
static __device__ __forceinline__ float bf2f(u16 s) {
  unsigned int u = ((unsigned int)s) << 16;
  union { unsigned int u; float f; } c; c.u = u; return c.f;
}

// ---------------------------------------------------------------------------
// prep: blocks 0..BB-1 normalize e -> XC0 (B,16,N) + XN0 (B,N,16), bf16,
// channels 1..15 zero.  Block BB converts W0/W1/W2 to bf16 (Wp0 zero-padded
// into the K=32 cat frame: k=0 -> x ch0, k=16 -> t ch0).
// ---------------------------------------------------------------------------
__global__ __launch_bounds__(256) void prep_kernel(
    const float* __restrict__ e,
    const float* __restrict__ W0, const float* __restrict__ W1,
    const float* __restrict__ W2,
    u16* __restrict__ XC0, u16* __restrict__ XN0,
    u16* __restrict__ Wp0, u16* __restrict__ Wp1, u16* __restrict__ Wp2) {
  int b = blockIdx.x;
  int tid = threadIdx.x;
  __shared__ float row[NN];
  __shared__ float red[256];

  if (b == BB) {  // weight conversion block
    for (int i = tid; i < 32 * 32; i += 256) {
      int o = i >> 5, k = i & 31;
      float v = (k == 0) ? W0[o * 2] : (k == 16) ? W0[o * 2 + 1] : 0.f;
      Wp0[i] = f2bf(v);
    }
    for (int i = tid; i < 64 * 64; i += 256) Wp1[i] = f2bf(W1[i]);
    for (int i = tid; i < 64 * 128; i += 256) Wp2[i] = f2bf(W2[i]);
    return;
  }

  const float* er = e + (size_t)b * NN;
  float s = 0.f;
  for (int i = tid; i < NN; i += 256) { float v = er[i]; row[i] = v; s += v; }
  red[tid] = s; __syncthreads();
  for (int off = 128; off > 0; off >>= 1) {
    if (tid < off) red[tid] += red[tid + off];
    __syncthreads();
  }
  float mu = red[0] * (1.f / NN);
  __syncthreads();
  float s2 = 0.f;
  for (int i = tid; i < NN; i += 256) { float d = row[i] - mu; s2 += d * d; }
  red[tid] = s2; __syncthreads();
  for (int off = 128; off > 0; off >>= 1) {
    if (tid < off) red[tid] += red[tid + off];
    __syncthreads();
  }
  float sd = sqrtf(red[0] * (1.f / NN));
  float inv = 1.f / (sd + EPSV);

  for (int i = tid; i < NN; i += 256) {
    float v = (row[i] - mu) * inv;
    u16 bits = f2bf(v);
    XC0[(size_t)b * 16 * NN + i] = bits;
    short8 a = (short8){0, 0, 0, 0, 0, 0, 0, 0};
    a[0] = (short)bits;
    short8 zz = (short8){0, 0, 0, 0, 0, 0, 0, 0};
    *(short8*)&XN0[((size_t)b * NN + i) * 16] = a;
    *(short8*)&XN0[((size_t)b * NN + i) * 16 + 8] = zz;
  }
  for (int c = 1; c < 16; ++c)
    for (int i = tid; i < NN; i += 256)
      XC0[((size_t)b * 16 + c) * NN + i] = 0;
}

// ---------------------------------------------------------------------------
// gather: t^T = adj @ x^T per batch, adj generated in registers (MFMA A-frag
// layout), B-operand from channel-major slab staged via global_load_lds.
// Output TT node-major (B,N,CB).
// ---------------------------------------------------------------------------
template<int CB>
__global__ __launch_bounds__(256) void gatherT_kernel(
    const u16* __restrict__ XC,     // (B, CB, N) bf16
    const float* __restrict__ phi,  // (B, N)
    const float* __restrict__ eta,  // (B, N)
    u16* __restrict__ TT)           // (B, N, CB) bf16
{
  constexpr int NCT = CB / 16;
  constexpr int SLAB = 32 * CB;
  constexpr int STH = CB * 4;

  __shared__ float2 pe[NN];
  __shared__ u16 slab[2][SLAB];

  int b = blockIdx.y;
  int m0 = blockIdx.x * 64;
  int tid = threadIdx.x;
  int lane = tid & 63;
  int w = tid >> 6;
  int g = lane >> 4;
  int cl = lane & 15;

  const float* phb = phi + (size_t)b * NN;
  const float* etb = eta + (size_t)b * NN;

  for (int i = tid; i < NN; i += 256)
    pe[i] = make_float2(phb[i], etb[i]);

  int m_lane = m0 + w * 16 + cl;
  float phm = phb[m_lane];
  float etm = etb[m_lane];

  f32x4 acc[NCT];
#pragma unroll
  for (int ci = 0; ci < NCT; ++ci) acc[ci] = (f32x4){0.f, 0.f, 0.f, 0.f};

  const u16* xb = XC + (size_t)b * CB * NN;

  if (tid < STH) {
    int gg = tid / CB, cc = tid % CB;
    gload_lds16(xb + (size_t)cc * NN + gg * 8, &slab[0][tid * 8]);
  }
  __syncthreads();

  for (int s = 0; s < NN / 32; ++s) {
    int cur = s & 1;
    if (s + 1 < NN / 32) {
      if (tid < STH) {
        int gg = tid / CB, cc = tid % CB;
        gload_lds16(xb + (size_t)cc * NN + (s + 1) * 32 + gg * 8,
                    &slab[cur ^ 1][tid * 8]);
      }
    }
    int n0 = s * 32;

    const float2* pp = &pe[n0 + 8 * g];
    union { short8 v; u16 h[8]; } af;
#pragma unroll
    for (int j = 0; j < 8; ++j) {
      float2 q = pp[j];
      float dp = q.x - phm;
      float de = q.y - etm;
      float d2 = fmaf(dp, dp, de * de);
      af.h[j] = f2bf(__expf(-d2));
    }

#pragma unroll
    for (int ci = 0; ci < NCT; ++ci) {
      const short8* bp = (const short8*)&slab[cur][(g * CB + ci * 16 + cl) * 8];
      acc[ci] = __builtin_amdgcn_mfma_f32_16x16x32_bf16(af.v, *bp, acc[ci], 0, 0, 0);
    }
    __syncthreads();
  }

#pragma unroll
  for (int ci = 0; ci < NCT; ++ci)
#pragma unroll
    for (int r = 0; r < 4; ++r) {
      int m = m0 + w * 16 + g * 4 + r;
      TT[((size_t)b * NN + m) * CB + ci * 16 + cl] = f2bf(acc[ci][r]);
    }
}

// ---------------------------------------------------------------------------
// proj (MFMA): z[m][o] = act( cat[m][k] . Wp[o][k] + bias[o] ), K = 2*CE.
//   A = cat tile (16m x K) from padded LDS; B = Wp^T from padded LDS.
//   Writes ZN node-major directly; ZC channel-major via LDS transpose.
// ---------------------------------------------------------------------------
template<int CE, int O, bool RELU>
__global__ __launch_bounds__(256) void projm_kernel(
    const u16* __restrict__ XN,   // (B,N,CE)
    const u16* __restrict__ TT,   // (B,N,CE)
    const u16* __restrict__ Wp,   // (O,2CE) bf16 dense
    const float* __restrict__ bias,
    u16* __restrict__ ZN,         // (B,N,O)
    u16* __restrict__ ZC)         // (B,O,N)
{
  constexpr int KW = 2 * CE;
  constexpr int S = KW + 8;      // padded LDS stride (multiple of 8 -> 16B align)
  constexpr int KS = KW / 32;    // K-steps
  constexpr int OT = O / 16;     // o-tiles
  __shared__ __align__(16) u16 cat[64 * S];
  __shared__ __align__(16) u16 wl[O * S];
  __shared__ u16 zt[64 * (O + 8)];

  int b = blockIdx.y;
  int m0 = blockIdx.x * 64;
  int tid = threadIdx.x;
  int lane = tid & 63, w = tid >> 6, g = lane >> 4, cl = lane & 15;

  constexpr int CV = CE / 8;
  for (int v = tid; v < 64 * CV; v += 256) {
    int m = v / CV, cv = v % CV;
    *(short8*)&cat[m * S + cv * 8] =
        *(const short8*)&XN[((size_t)b * NN + m0 + m) * CE + cv * 8];
  }
  for (int v = tid; v < 64 * CV; v += 256) {
    int m = v / CV, cv = v % CV;
    *(short8*)&cat[m * S + CE + cv * 8] =
        *(const short8*)&TT[((size_t)b * NN + m0 + m) * CE + cv * 8];
  }
  constexpr int WV = KW / 8;
  for (int v = tid; v < O * WV; v += 256) {
    int o = v / WV, cv = v % WV;
    *(short8*)&wl[o * S + cv * 8] = *(const short8*)&Wp[o * KW + cv * 8];
  }
  __syncthreads();

  short8 af[KS];
#pragma unroll
  for (int kk = 0; kk < KS; ++kk)
    af[kk] = *(const short8*)&cat[(w * 16 + cl) * S + kk * 32 + g * 8];

  f32x4 acc[OT];
#pragma unroll
  for (int oi = 0; oi < OT; ++oi) acc[oi] = (f32x4){0.f, 0.f, 0.f, 0.f};
#pragma unroll
  for (int oi = 0; oi < OT; ++oi)
#pragma unroll
    for (int kk = 0; kk < KS; ++kk) {
      short8 bfr = *(const short8*)&wl[(oi * 16 + cl) * S + kk * 32 + g * 8];
      acc[oi] = __builtin_amdgcn_mfma_f32_16x16x32_bf16(af[kk], bfr, acc[oi], 0, 0, 0);
    }

#pragma unroll
  for (int oi = 0; oi < OT; ++oi) {
    float bz = bias[oi * 16 + cl];
#pragma unroll
    for (int r = 0; r < 4; ++r) {
      float z = acc[oi][r] + bz;
      if (RELU) z = fmaxf(z, 0.f);
      u16 zb = f2bf(z);
      int m = w * 16 + 4 * g + r;
      ZN[((size_t)b * NN + m0 + m) * O + oi * 16 + cl] = zb;
      zt[m * (O + 8) + oi * 16 + cl] = zb;
    }
  }
  __syncthreads();
  for (int idx = tid; idx < 64 * O; idx += 256) {
    int m = idx & 63, o = idx >> 6;
    ZC[((size_t)b * O + o) * NN + m0 + m] = zt[m * (O + 8) + o];
  }
}

// ---------------------------------------------------------------------------
// proj3out: layer-3 projection (C=64 -> O=1) + mean + sigmoid, bf16 inputs
// ---------------------------------------------------------------------------
__global__ __launch_bounds__(256) void proj3out_kernel(
    const u16* __restrict__ XN,   // (B, N, 64) bf16
    const u16* __restrict__ TT,   // (B, N, 64) bf16
    const float* __restrict__ Wm, // (1, 128)
    const float* __restrict__ bias,
    float* __restrict__ out)      // (B)
{
  int b = blockIdx.x;
  int tid = threadIdx.x;
  __shared__ float sW[128];
  __shared__ float red[256];
  if (tid < 128) sW[tid] = Wm[tid];
  __syncthreads();

  float s = 0.f;
  for (int k2 = 0; k2 < 4; ++k2) {
    int m = k2 * 256 + tid;
    const u16* xr = XN + ((size_t)b * NN + m) * 64;
    const u16* tr = TT + ((size_t)b * NN + m) * 64;
    float z = bias[0];
#pragma unroll
    for (int c8 = 0; c8 < 8; ++c8) {
      short8 xv = *(const short8*)&xr[c8 * 8];
      short8 tv = *(const short8*)&tr[c8 * 8];
#pragma unroll
      for (int j = 0; j < 8; ++j) {
        z = fmaf(sW[c8 * 8 + j], bf2f((u16)xv[j]), z);
        z = fmaf(sW[64 + c8 * 8 + j], bf2f((u16)tv[j]), z);
      }
    }
    s += z;
  }
  red[tid] = s; __syncthreads();
  for (int off = 128; off > 0; off >>= 1) {
    if (tid < off) red[tid] += red[tid + off];
    __syncthreads();
  }
  if (tid == 0) {
    float mval = red[0] * (1.f / NN);
    out[b] = 1.f / (1.f + __expf(-mval));
  }
}

// ---------------------------------------------------------------------------
extern "C" void kernel_launch(void* const* d_in, const int* in_sizes, int n_in,
                              void* d_out, int out_size, void* d_ws, size_t ws_size,
                              hipStream_t stream) {
  const float* e   = (const float*)d_in[0];
  const float* phi = (const float*)d_in[1];
  const float* eta = (const float*)d_in[2];
  const float* W0  = (const float*)d_in[3];
  const float* b0  = (const float*)d_in[4];
  const float* W1  = (const float*)d_in[5];
  const float* b1  = (const float*)d_in[6];
  const float* W2  = (const float*)d_in[7];
  const float* b2  = (const float*)d_in[8];
  const float* W3  = (const float*)d_in[9];
  const float* b3  = (const float*)d_in[10];

  // ws layout (<= 48 MB, all bf16 except nothing):
  //  [ 0, 8M) TT    per-layer gather output (B,N,CE)
  //  [ 8,10M) XC0   (B,16,N)       [dead after g0]   } region reused
  //  [10,12M) XN0   (B,N,16)       [dead after p0]   } by XC3 at [8,16M)
  //  [12,16M) XC1   (B,32,N)       [dead after g1]   }
  //  [16,20M) XN1   (B,N,32)       [dead after p1]
  //  [20,28M) XC2   (B,64,N)       [dead after g2]
  //  [28,36M) XN2   (B,N,64)       [dead after p2]
  //  [ 8,16M) XC3   (B,64,N)       written by p2
  //  [36,44M) XN3   (B,N,64)       written by p2
  //  [44M..)  Wp0 (32x32), Wp1 (64x64), Wp2 (64x128) bf16
  char* wsb = (char*)d_ws;
  const size_t MB = 1u << 20;
  u16* TT  = (u16*)(wsb);
  u16* XC0 = (u16*)(wsb + 8 * MB);
  u16* XN0 = (u16*)(wsb + 10 * MB);
  u16* XC1 = (u16*)(wsb + 12 * MB);
  u16* XN1 = (u16*)(wsb + 16 * MB);
  u16* XC2 = (u16*)(wsb + 20 * MB);
  u16* XN2 = (u16*)(wsb + 28 * MB);
  u16* XC3 = (u16*)(wsb + 8 * MB);
  u16* XN3 = (u16*)(wsb + 36 * MB);
  u16* Wp0 = (u16*)(wsb + 44 * MB);
  u16* Wp1 = Wp0 + 32 * 32;
  u16* Wp2 = Wp1 + 64 * 64;

  dim3 blk(256);
  dim3 gg(NN / 64, BB);   // 1024 blocks for gather & proj

  prep_kernel<<<BB + 1, blk, 0, stream>>>(e, W0, W1, W2, XC0, XN0, Wp0, Wp1, Wp2);

  // Layer 0: CE=16 (C=1 padded) -> O=32
  gatherT_kernel<16><<<gg, blk, 0, stream>>>(XC0, phi, eta, TT);
  projm_kernel<16, 32, true><<<gg, blk, 0, stream>>>(XN0, TT, Wp0, b0, XN1, XC1);

  // Layer 1: CE=32 -> O=64
  gatherT_kernel<32><<<gg, blk, 0, stream>>>(XC1, phi, eta, TT);
  projm_kernel<32, 64, true><<<gg, blk, 0, stream>>>(XN1, TT, Wp1, b1, XN2, XC2);

  // Layer 2: CE=64 -> O=64
  gatherT_kernel<64><<<gg, blk, 0, stream>>>(XC2, phi, eta, TT);
  projm_kernel<64, 64, true><<<gg, blk, 0, stream>>>(XN2, TT, Wp2, b2, XN3, XC3);

  // Layer 3: CE=64 -> O=1, fused with mean+sigmoid
  gatherT_kernel<64><<<gg, blk, 0, stream>>>(XC3, phi, eta, TT);
  proj3out_kernel<<<BB, blk, 0, stream>>>(XN3, TT, W3, b3, (float*)d_out);
}

// Round 9
// 121.318 us; speedup vs baseline: 7.4690x; 1.1893x over previous
//
#include <hip/hip_runtime.h>
#include <hip/hip_bf16.h>
#include <math.h>

#define BB 64
#define NN 1024
#define EPSV 1e-5f

typedef unsigned short u16;
typedef __attribute__((ext_vector_type(8))) short short8;
typedef __attribute__((ext_vector_type(4))) float f32x4;

#define GLOBAL_AS __attribute__((address_space(1)))
#define LDS_AS __attribute__((address_space(3)))

static __device__ __forceinline__ void gload_lds16(const void* g, void* l) {
  __builtin_amdgcn_global_load_lds((const GLOBAL_AS unsigned int*)g,
                                   (LDS_AS unsigned int*)l, 16, 0, 0);
}

static __device__ __forceinline__ u16 f2bf(float f) {
  __hip_bfloat16 h = __float2bfloat16(f);   // RNE
  union { __hip_bfloat16 h; u16 s; } u; u.h = h; return u.s;
}
static __device__ __forceinline__ float bf2f(u16 s) {
  unsigned int u = ((unsigned int)s) << 16;
  union { unsigned int u; float f; } c; c.u = u; return c.f;
}

// ---------------------------------------------------------------------------
// prep: blocks 0..BB-1 normalize e -> XC0 (B,16,N) + XN0 (B,N,16) bf16,
// channels 1..15 zero.  Block BB converts W0/W1/W2 to bf16 (Wp0 zero-padded
// into the K=32 cat frame: k=0 -> x ch0, k=16 -> t ch0).
// ---------------------------------------------------------------------------
__global__ __launch_bounds__(256) void prep_kernel(
    const float* __restrict__ e,
    const float* __restrict__ W0, const float* __restrict__ W1,
    const float* __restrict__ W2,
    u16* __restrict__ XC0, u16* __restrict__ XN0,
    u16* __restrict__ Wp0, u16* __restrict__ Wp1, u16* __restrict__ Wp2) {
  int b = blockIdx.x;
  int tid = threadIdx.x;
  __shared__ float row[NN];
  __shared__ float red[256];

  if (b == BB) {  // weight conversion block
    for (int i = tid; i < 32 * 32; i += 256) {
      int o = i >> 5, k = i & 31;
      float v = (k == 0) ? W0[o * 2] : (k == 16) ? W0[o * 2 + 1] : 0.f;
      Wp0[i] = f2bf(v);
    }
    for (int i = tid; i < 64 * 64; i += 256) Wp1[i] = f2bf(W1[i]);
    for (int i = tid; i < 64 * 128; i += 256) Wp2[i] = f2bf(W2[i]);
    return;
  }

  const float* er = e + (size_t)b * NN;
  float s = 0.f;
  for (int i = tid; i < NN; i += 256) { float v = er[i]; row[i] = v; s += v; }
  red[tid] = s; __syncthreads();
  for (int off = 128; off > 0; off >>= 1) {
    if (tid < off) red[tid] += red[tid + off];
    __syncthreads();
  }
  float mu = red[0] * (1.f / NN);
  __syncthreads();
  float s2 = 0.f;
  for (int i = tid; i < NN; i += 256) { float d = row[i] - mu; s2 += d * d; }
  red[tid] = s2; __syncthreads();
  for (int off = 128; off > 0; off >>= 1) {
    if (tid < off) red[tid] += red[tid + off];
    __syncthreads();
  }
  float sd = sqrtf(red[0] * (1.f / NN));
  float inv = 1.f / (sd + EPSV);

  for (int i = tid; i < NN; i += 256) {
    float v = (row[i] - mu) * inv;
    u16 bits = f2bf(v);
    XC0[(size_t)b * 16 * NN + i] = bits;
    short8 a = (short8){0, 0, 0, 0, 0, 0, 0, 0};
    a[0] = (short)bits;
    short8 zz = (short8){0, 0, 0, 0, 0, 0, 0, 0};
    *(short8*)&XN0[((size_t)b * NN + i) * 16] = a;
    *(short8*)&XN0[((size_t)b * NN + i) * 16 + 8] = zz;
  }
  for (int c = 1; c < 16; ++c)
    for (int i = tid; i < NN; i += 256)
      XC0[((size_t)b * 16 + c) * NN + i] = 0;
}

// ---------------------------------------------------------------------------
// fused layer:  gather (t^T = adj @ x^T, adj generated in registers in MFMA
// A-frag layout; B staged from channel-major XC via global_load_lds, NT=64,
// double-buffered) THEN projection (MFMA over cat=[x|t], W bf16 in LDS) in
// the SAME block.  t never touches global memory.
//   phase1 LDS: [pe 8K | slab 2*NT*CE*2B]
//   phase2 LDS: [cat 64*S*2B | W O*S*2B], zt overlays cat after proj reads.
// Writes ZN (B,N,O) node-major and ZC (B,O,N) channel-major.
// ---------------------------------------------------------------------------
template<int CE, int O>
__global__ __launch_bounds__(256, 4) void fused_kernel(
    const u16* __restrict__ XC,     // (B,CE,N) bf16
    const u16* __restrict__ XN,     // (B,N,CE) bf16
    const float* __restrict__ phi,  // (B,N)
    const float* __restrict__ eta,  // (B,N)
    const u16* __restrict__ Wp,     // (O,2CE) bf16
    const float* __restrict__ bias, // (O)
    u16* __restrict__ ZN,           // (B,N,O)
    u16* __restrict__ ZC)           // (B,O,N)
{
  constexpr int NCT = CE / 16;          // B-tiles per wave in gather
  constexpr int NT = 64;                // n per staging macro-step
  constexpr int SLABV = NT * CE / 8;    // 16B vectors per slab
  constexpr int KW = 2 * CE;
  constexpr int S = KW + 8;             // padded LDS stride (u16)
  constexpr int OT = O / 16;
  constexpr int KS = KW / 32;

  constexpr int PH1 = (int)sizeof(float2) * NN + 2 * NT * CE * 2;
  constexpr int PH2 = (64 + O) * S * 2;
  constexpr int SM = PH1 > PH2 ? PH1 : PH2;
  __shared__ __align__(16) char smem[SM];
  float2* pe = (float2*)smem;
  u16* slab0 = (u16*)(smem + sizeof(float2) * NN);
  u16* slab1 = slab0 + NT * CE;
  u16* cat = (u16*)smem;
  u16* wl  = (u16*)smem + 64 * S;
  u16* zt  = (u16*)smem;                // overlays cat after proj A-reads

  int b = blockIdx.y;
  int m0 = blockIdx.x * 64;
  int tid = threadIdx.x;
  int lane = tid & 63, w = tid >> 6, g = lane >> 4, cl = lane & 15;

  const float* phb = phi + (size_t)b * NN;
  const float* etb = eta + (size_t)b * NN;
  for (int i = tid; i < NN; i += 256)
    pe[i] = make_float2(phb[i], etb[i]);

  int m_lane = m0 + w * 16 + cl;
  float phm = phb[m_lane];
  float etm = etb[m_lane];

  f32x4 acc[NCT];
#pragma unroll
  for (int ci = 0; ci < NCT; ++ci) acc[ci] = (f32x4){0.f, 0.f, 0.f, 0.f};

  const u16* xb = XC + (size_t)b * CE * NN;

  for (int v = tid; v < SLABV; v += 256) {
    int gg = v / CE, cc = v % CE;
    gload_lds16(xb + (size_t)cc * NN + gg * 8, slab0 + v * 8);
  }
  __syncthreads();

  for (int s = 0; s < NN / NT; ++s) {
    u16* curp = (s & 1) ? slab1 : slab0;
    u16* nxtp = (s & 1) ? slab0 : slab1;
    if (s + 1 < NN / NT) {
      for (int v = tid; v < SLABV; v += 256) {
        int gg = v / CE, cc = v % CE;
        gload_lds16(xb + (size_t)cc * NN + (s + 1) * NT + gg * 8, nxtp + v * 8);
      }
    }
    int n0 = s * NT;
#pragma unroll
    for (int kc = 0; kc < NT / 32; ++kc) {
      const float2* pp = &pe[n0 + kc * 32 + 8 * g];
      union { short8 v; u16 h[8]; } af;
#pragma unroll
      for (int j = 0; j < 8; ++j) {
        float2 q = pp[j];
        float dp = q.x - phm;
        float de = q.y - etm;
        float d2 = fmaf(dp, dp, de * de);
        af.h[j] = f2bf(__expf(-d2));
      }
#pragma unroll
      for (int ci = 0; ci < NCT; ++ci) {
        const short8* bp =
            (const short8*)&curp[((kc * 4 + g) * CE + ci * 16 + cl) * 8];
        acc[ci] = __builtin_amdgcn_mfma_f32_16x16x32_bf16(af.v, *bp, acc[ci], 0, 0, 0);
      }
    }
    __syncthreads();
  }

  // ---- phase 2: projection (pe/slab dead; cat/wl overlay) ----
  // t part from acc regs (D layout: row=(lane>>4)*4+r, col=lane&15)
#pragma unroll
  for (int ci = 0; ci < NCT; ++ci)
#pragma unroll
    for (int r = 0; r < 4; ++r) {
      int m = w * 16 + g * 4 + r;
      cat[m * S + CE + ci * 16 + cl] = f2bf(acc[ci][r]);
    }
  // x part from XN
  constexpr int CV = CE / 8;
  for (int v = tid; v < 64 * CV; v += 256) {
    int m = v / CV, cv = v % CV;
    *(short8*)&cat[m * S + cv * 8] =
        *(const short8*)&XN[((size_t)b * NN + m0 + m) * CE + cv * 8];
  }
  // W
  constexpr int WV = KW / 8;
  for (int v = tid; v < O * WV; v += 256) {
    int o = v / WV, cv = v % WV;
    *(short8*)&wl[o * S + cv * 8] = *(const short8*)&Wp[o * KW + cv * 8];
  }
  __syncthreads();

  short8 afp[KS];
#pragma unroll
  for (int kk = 0; kk < KS; ++kk)
    afp[kk] = *(const short8*)&cat[(w * 16 + cl) * S + kk * 32 + g * 8];

  f32x4 pacc[OT];
#pragma unroll
  for (int oi = 0; oi < OT; ++oi) pacc[oi] = (f32x4){0.f, 0.f, 0.f, 0.f};
#pragma unroll
  for (int oi = 0; oi < OT; ++oi)
#pragma unroll
    for (int kk = 0; kk < KS; ++kk) {
      short8 bfr = *(const short8*)&wl[(oi * 16 + cl) * S + kk * 32 + g * 8];
      pacc[oi] = __builtin_amdgcn_mfma_f32_16x16x32_bf16(afp[kk], bfr, pacc[oi], 0, 0, 0);
    }
  __syncthreads();  // all cat reads done before zt overlay

#pragma unroll
  for (int oi = 0; oi < OT; ++oi) {
    float bz = bias[oi * 16 + cl];
#pragma unroll
    for (int r = 0; r < 4; ++r) {
      float z = fmaxf(pacc[oi][r] + bz, 0.f);   // relu (all fused layers)
      u16 zb = f2bf(z);
      int m = w * 16 + 4 * g + r;
      ZN[((size_t)b * NN + m0 + m) * O + oi * 16 + cl] = zb;
      zt[m * (O + 8) + oi * 16 + cl] = zb;
    }
  }
  __syncthreads();
  for (int idx = tid; idx < 64 * O; idx += 256) {
    int m = idx & 63, o = idx >> 6;
    ZC[((size_t)b * O + o) * NN + m0 + m] = zt[m * (O + 8) + o];
  }
}

// ---------------------------------------------------------------------------
// fused last layer: gather (CE=64) + scalar dot with W3 (O=1) + block partial
// ---------------------------------------------------------------------------
__global__ __launch_bounds__(256, 4) void fused_last_kernel(
    const u16* __restrict__ XC,     // (B,64,N)
    const u16* __restrict__ XN,     // (B,N,64)
    const float* __restrict__ phi,
    const float* __restrict__ eta,
    const float* __restrict__ W3,   // (1,128) fp32
    const float* __restrict__ b3,
    float* __restrict__ partial)    // (B,16)
{
  constexpr int CE = 64, NCT = 4, NT = 64;
  constexpr int SLABV = NT * CE / 8;
  constexpr int S = 136;            // cat stride (2*CE + 8)

  constexpr int PH1 = (int)sizeof(float2) * NN + 2 * NT * CE * 2;  // 24.5KB
  __shared__ __align__(16) char smem[PH1];
  float2* pe = (float2*)smem;
  u16* slab0 = (u16*)(smem + sizeof(float2) * NN);
  u16* slab1 = slab0 + NT * CE;
  u16* cat = (u16*)smem;            // 64*S*2 = 17408B, overlays phase1
  __shared__ float sW[128];
  __shared__ float red[256];

  int b = blockIdx.y;
  int m0 = blockIdx.x * 64;
  int tid = threadIdx.x;
  int lane = tid & 63, w = tid >> 6, g = lane >> 4, cl = lane & 15;

  const float* phb = phi + (size_t)b * NN;
  const float* etb = eta + (size_t)b * NN;
  for (int i = tid; i < NN; i += 256)
    pe[i] = make_float2(phb[i], etb[i]);
  if (tid < 128) sW[tid] = W3[tid];

  int m_lane = m0 + w * 16 + cl;
  float phm = phb[m_lane];
  float etm = etb[m_lane];

  f32x4 acc[NCT];
#pragma unroll
  for (int ci = 0; ci < NCT; ++ci) acc[ci] = (f32x4){0.f, 0.f, 0.f, 0.f};

  const u16* xb = XC + (size_t)b * CE * NN;

  for (int v = tid; v < SLABV; v += 256) {
    int gg = v / CE, cc = v % CE;
    gload_lds16(xb + (size_t)cc * NN + gg * 8, slab0 + v * 8);
  }
  __syncthreads();

  for (int s = 0; s < NN / NT; ++s) {
    u16* curp = (s & 1) ? slab1 : slab0;
    u16* nxtp = (s & 1) ? slab0 : slab1;
    if (s + 1 < NN / NT) {
      for (int v = tid; v < SLABV; v += 256) {
        int gg = v / CE, cc = v % CE;
        gload_lds16(xb + (size_t)cc * NN + (s + 1) * NT + gg * 8, nxtp + v * 8);
      }
    }
    int n0 = s * NT;
#pragma unroll
    for (int kc = 0; kc < NT / 32; ++kc) {
      const float2* pp = &pe[n0 + kc * 32 + 8 * g];
      union { short8 v; u16 h[8]; } af;
#pragma unroll
      for (int j = 0; j < 8; ++j) {
        float2 q = pp[j];
        float dp = q.x - phm;
        float de = q.y - etm;
        float d2 = fmaf(dp, dp, de * de);
        af.h[j] = f2bf(__expf(-d2));
      }
#pragma unroll
      for (int ci = 0; ci < NCT; ++ci) {
        const short8* bp =
            (const short8*)&curp[((kc * 4 + g) * CE + ci * 16 + cl) * 8];
        acc[ci] = __builtin_amdgcn_mfma_f32_16x16x32_bf16(af.v, *bp, acc[ci], 0, 0, 0);
      }
    }
    __syncthreads();
  }

  // ---- phase 2: scalar dot z[m] = W3 . cat[m] ; partial = sum_m z[m] ----
#pragma unroll
  for (int ci = 0; ci < NCT; ++ci)
#pragma unroll
    for (int r = 0; r < 4; ++r) {
      int m = w * 16 + g * 4 + r;
      cat[m * S + CE + ci * 16 + cl] = f2bf(acc[ci][r]);
    }
  for (int v = tid; v < 64 * 8; v += 256) {
    int m = v / 8, cv = v % 8;
    *(short8*)&cat[m * S + cv * 8] =
        *(const short8*)&XN[((size_t)b * NN + m0 + m) * CE + cv * 8];
  }
  __syncthreads();

  int m = tid & 63, q = tid >> 6;
  float sacc = 0.f;
#pragma unroll
  for (int k = 0; k < 32; ++k) {
    int kk = q * 32 + k;
    sacc = fmaf(sW[kk], bf2f(cat[m * S + kk]), sacc);  // cat col == k (x:0-63, t:64-127)
  }
  red[tid] = sacc; __syncthreads();
  for (int off = 128; off > 0; off >>= 1) {
    if (tid < off) red[tid] += red[tid + off];
    __syncthreads();
  }
  if (tid == 0)
    partial[b * 16 + blockIdx.x] = red[0] + 64.f * b3[0];
}

// ---------------------------------------------------------------------------
// final: out[b] = sigmoid( sum_i partial[b][i] / N )
// ---------------------------------------------------------------------------
__global__ __launch_bounds__(64) void final_kernel(const float* __restrict__ partial,
                                                   float* __restrict__ out) {
  int b = blockIdx.x;
  int lane = threadIdx.x;
  float v = (lane < 16) ? partial[b * 16 + lane] : 0.f;
#pragma unroll
  for (int off = 8; off > 0; off >>= 1) v += __shfl_down(v, off);
  if (lane == 0) out[b] = 1.f / (1.f + __expf(-(v * (1.f / NN))));
}

// ---------------------------------------------------------------------------
extern "C" void kernel_launch(void* const* d_in, const int* in_sizes, int n_in,
                              void* d_out, int out_size, void* d_ws, size_t ws_size,
                              hipStream_t stream) {
  const float* e   = (const float*)d_in[0];
  const float* phi = (const float*)d_in[1];
  const float* eta = (const float*)d_in[2];
  const float* W0  = (const float*)d_in[3];
  const float* b0  = (const float*)d_in[4];
  const float* W1  = (const float*)d_in[5];
  const float* b1  = (const float*)d_in[6];
  const float* W2  = (const float*)d_in[7];
  const float* b2  = (const float*)d_in[8];
  const float* W3  = (const float*)d_in[9];
  const float* b3  = (const float*)d_in[10];

  // ws layout:
  //  [0, 8M)  PB partials (B*16 f32) at offset 0; rest free
  //  [ 8,10M) XC0 (B,16,N)   [10,12M) XN0 (B,N,16)
  //  [12,16M) XC1 (B,32,N)   [16,20M) XN1 (B,N,32)
  //  [20,28M) XC2 (B,64,N)   [28,36M) XN2 (B,N,64)
  //  [ 8,16M) XC3 (B,64,N)  (overlays XC0/XN0/XC1 — all dead by layer 2)
  //  [36,44M) XN3 (B,N,64)
  //  [44M..)  Wp0 (32x32), Wp1 (64x64), Wp2 (64x128) bf16
  char* wsb = (char*)d_ws;
  const size_t MB = 1u << 20;
  float* PB = (float*)(wsb);
  u16* XC0 = (u16*)(wsb + 8 * MB);
  u16* XN0 = (u16*)(wsb + 10 * MB);
  u16* XC1 = (u16*)(wsb + 12 * MB);
  u16* XN1 = (u16*)(wsb + 16 * MB);
  u16* XC2 = (u16*)(wsb + 20 * MB);
  u16* XN2 = (u16*)(wsb + 28 * MB);
  u16* XC3 = (u16*)(wsb + 8 * MB);
  u16* XN3 = (u16*)(wsb + 36 * MB);
  u16* Wp0 = (u16*)(wsb + 44 * MB);
  u16* Wp1 = Wp0 + 32 * 32;
  u16* Wp2 = Wp1 + 64 * 64;

  dim3 blk(256);
  dim3 gg(NN / 64, BB);   // 1024 blocks

  prep_kernel<<<BB + 1, blk, 0, stream>>>(e, W0, W1, W2, XC0, XN0, Wp0, Wp1, Wp2);

  // Layer 0: CE=16 (C=1 padded) -> O=32
  fused_kernel<16, 32><<<gg, blk, 0, stream>>>(XC0, XN0, phi, eta, Wp0, b0, XN1, XC1);
  // Layer 1: CE=32 -> O=64
  fused_kernel<32, 64><<<gg, blk, 0, stream>>>(XC1, XN1, phi, eta, Wp1, b1, XN2, XC2);
  // Layer 2: CE=64 -> O=64
  fused_kernel<64, 64><<<gg, blk, 0, stream>>>(XC2, XN2, phi, eta, Wp2, b2, XN3, XC3);
  // Layer 3: CE=64 -> O=1, fused dot + partials
  fused_last_kernel<<<gg, blk, 0, stream>>>(XC3, XN3, phi, eta, W3, b3, PB);

  final_kernel<<<BB, dim3(64), 0, stream>>>(PB, (float*)d_out);
}